// Round 13
// baseline (436.176 us; speedup 1.0000x reference)
//
#include <hip/hip_runtime.h>

// GCNDecoder: B=2, N=40000, HID=128, E=640000, IN=3, OUT=3. Float tensors f32; indices int32.
//
// Round 27 = EXACT round-25 kernel (434.9 us, PASSED — best verified state).
//   r26's 64-row gemm tile failed first-call at 4.03e-3 with no locatable bug —
//   third such failure (r17 fusion 5.2e-3, r9 initw-vec post-timing drift).
//   Diagnosis: bf16-quantized 5-layer pipeline passes at 9.77e-4 with only 3.2x
//   threshold headroom; hipcc FMA-contraction/scheduling shifts under ANY value-path
//   restructure perturb intermediate roundings -> amplified to 3-6e-3. Value-path
//   kernel text is therefore FROZEN (initw since r10; gemm/spmm now too).
//   Probe ledger: spmm floor ~47.5 us (ILP/TLP/footprint/VALU all null or worse);
//   gaps ~0.3 us (r21); gemm occupancy lever unreachable (r26). Practical floor.

typedef unsigned short u16;
typedef unsigned int   u32;
typedef __bf16 bf8_t __attribute__((ext_vector_type(8)));
typedef float  f4_t  __attribute__((ext_vector_type(4)));
typedef float  f2_t  __attribute__((ext_vector_type(2)));

#define N_NODES 40000
#define N_EDGES 640000
#define BN      80000            // BATCH * N_NODES

__device__ __forceinline__ float bf2f(u16 u) {
  union { u32 i; float f; } v; v.i = ((u32)u) << 16; return v.f;
}
__device__ __forceinline__ u16 f2bf(float f) {
  union { float f; u32 i; } v; v.f = f;
  u32 i = v.i;
  return (u16)((i + 0x7FFFu + ((i >> 16) & 1u)) >> 16);   // RNE
}
__device__ __forceinline__ float asf(u32 i) {
  union { u32 u; float f; } v; v.u = i; return v.f;
}
__device__ __forceinline__ u32 pack2(float a, float b) {
  return (u32)f2bf(a) | ((u32)f2bf(b) << 16);
}
__device__ __forceinline__ float lo2f(u32 v) { return asf(v << 16); }
__device__ __forceinline__ float hi2f(u32 v) { return asf(v & 0xffff0000u); }
__device__ __forceinline__ u32 relu2(u32 v) {     // zero out negative bf16 halves (packed)
  u32 r = v;
  if (r & 0x8000u)     r &= 0xffff0000u;
  if (r & 0x80000000u) r &= 0x0000ffffu;
  return r;
}

#if defined(__has_builtin)
#if __has_builtin(__builtin_elementwise_max)
#define FMAX2Z(a) __builtin_elementwise_max((a), (f2_t){0.f, 0.f})
#endif
#endif
#ifndef FMAX2Z
#define FMAX2Z(a) ((f2_t){fmaxf((a).x, 0.f), fmaxf((a).y, 0.f)})
#endif

__global__ void fill_kernel(float* __restrict__ out, int n, float v) {
  int i = blockIdx.x * 256 + threadIdx.x;
  if (i < n) out[i] = v;
}

// ---------------- CSR scan (3-phase) + scatter ----------------
__global__ void scan1_kernel(const int* __restrict__ cnt, int* __restrict__ row_ptr,
                             int* __restrict__ blocksum) {
  __shared__ int sm[256];
  int t = threadIdx.x;
  int row = blockIdx.x * 256 + t;
  int v = (row < N_NODES) ? cnt[row] : 0;
  sm[t] = v; __syncthreads();
  for (int off = 1; off < 256; off <<= 1) {
    int u = (t >= off) ? sm[t - off] : 0;
    __syncthreads();
    sm[t] += u;
    __syncthreads();
  }
  if (row < N_NODES) row_ptr[row] = sm[t] - v;
  if (t == 255) blocksum[blockIdx.x] = sm[255];
}

__global__ void scan2_kernel(int* __restrict__ blocksum, int* __restrict__ row_ptr, int nblk) {
  __shared__ int sm[256];
  int t = threadIdx.x;
  int v = (t < nblk) ? blocksum[t] : 0;
  sm[t] = v; __syncthreads();
  for (int off = 1; off < 256; off <<= 1) {
    int u = (t >= off) ? sm[t - off] : 0;
    __syncthreads();
    sm[t] += u;
    __syncthreads();
  }
  if (t < nblk) blocksum[t] = sm[t] - v;
  if (t == 255) row_ptr[N_NODES] = sm[255];
}

__global__ void scan3_kernel(int* __restrict__ row_ptr, const int* __restrict__ blocksum,
                             int* __restrict__ cnt) {
  int row = blockIdx.x * 256 + threadIdx.x;
  if (row < N_NODES) {
    int rp = row_ptr[row] + blocksum[blockIdx.x];
    row_ptr[row] = rp;
    cnt[row] = rp;
  }
}

__global__ void scatter_kernel(const int* __restrict__ rows, const int* __restrict__ cols,
                               int* __restrict__ cur, int* __restrict__ cols_s) {
  int e = blockIdx.x * 256 + threadIdx.x;
  if (e < N_EDGES) {
    int r = rows[e];
    int pos = atomicAdd(&cur[r], 1);
    cols_s[pos] = cols[e];
  }
}

// ---------------- canonicalize CSR segment order (bit-determinism across calls) ----------
__global__ void sortcols_kernel(const int* __restrict__ row_ptr, int* __restrict__ cols_s) {
  int row = blockIdx.x * 4 + (threadIdx.x >> 6);   // grid 10000 * 4 waves = 40000 rows
  int l = threadIdx.x & 63;
  int s = row_ptr[row], e = row_ptr[row + 1];
  int deg = e - s;
  if (deg <= 1) return;                            // wave-uniform branch
  if (deg <= 64) {
    int v = (l < deg) ? cols_s[s + l] : 0x7fffffff;
#pragma unroll
    for (int k = 2; k <= 64; k <<= 1) {
#pragma unroll
      for (int j = k >> 1; j >= 1; j >>= 1) {
        int p = __shfl_xor(v, j);
        bool up = ((l & k) == 0);
        bool keepmin = (((l & j) == 0) == up);
        int mn = v < p ? v : p;
        int mx = v < p ? p : v;
        v = keepmin ? mn : mx;
      }
    }
    if (l < deg) cols_s[s + l] = v;
  } else if (l == 0) {                             // ultra-rare fallback: serial insertion
    for (int i = s + 1; i < e; ++i) {
      int key = cols_s[i];
      int j = i - 1;
      while (j >= s && cols_s[j] > key) { cols_s[j + 1] = cols_s[j]; --j; }
      cols_s[j + 1] = key;
    }
  }
}

// ---------------- merged: xb init (20000) + wprep (512) + hist (2500) ----------------
// FROZEN TEXT (r9 experiment: restructuring this broke post-timing determinism).
__global__ void initw_kernel(const float* __restrict__ p, const float* __restrict__ W,
                             const float* __restrict__ bias, u16* __restrict__ xb,
                             const float* __restrict__ Wf_b, const float* __restrict__ Ws_b,
                             const float* __restrict__ bf_b, const float* __restrict__ bs_b,
                             u16* __restrict__ WtCat, float* __restrict__ biasCat,
                             const int* __restrict__ erows, int* __restrict__ cnt) {
  if (blockIdx.x >= 20512) {                     // hist part: 2500 blocks
    int e = (blockIdx.x - 20512) * 256 + threadIdx.x;
    if (e < N_EDGES) atomicAdd(&cnt[erows[e]], 1);
    return;
  }
  if (blockIdx.x >= 20000) {                     // wprep part: 512 blocks
    int idx = (blockIdx.x - 20000) * 256 + threadIdx.x;   // 4*128*256 = 131072
    int g = idx >> 15, rem = idx & 32767;
    int h = rem >> 8, k = rem & 255;
    float v = (k < 128) ? Ws_b[(g * 128 + k) * 128 + h]
                        : Wf_b[(g * 128 + (k - 128)) * 128 + h];
    WtCat[idx] = f2bf(v);
    if (k == 0) biasCat[g * 128 + h] = bs_b[g * 128 + h] + bf_b[g * 128 + h];
    return;
  }
  int idx = blockIdx.x * 256 + threadIdx.x;      // BN*64 = 5,120,000
  int row = idx >> 6;
  int h = (idx & 63) * 2;
  float p0 = p[row * 3], p1 = p[row * 3 + 1], p2 = p[row * 3 + 2];
  float s0 = p0 * W[h]     + p1 * W[128 + h]     + p2 * W[256 + h]     + bias[h];
  float s1 = p0 * W[h + 1] + p1 * W[128 + h + 1] + p2 * W[256 + h + 1] + bias[h + 1];
  ((u32*)xb)[(size_t)row * 64 + (h >> 1)] = pack2(s0, s1);
}

// ---------------- gather SPMM, batch-split, float2/pk accumulators (r25, verified) ------
#define ACCP2(u, A0, A1, A2, A3) {                                        \
  f2_t t0, t1, t2, t3;                                                    \
  t0.x = asf((u).x << 16); t0.y = asf((u).x & 0xffff0000u);               \
  t1.x = asf((u).y << 16); t1.y = asf((u).y & 0xffff0000u);               \
  t2.x = asf((u).z << 16); t2.y = asf((u).z & 0xffff0000u);               \
  t3.x = asf((u).w << 16); t3.y = asf((u).w & 0xffff0000u);               \
  A0 += t0; A1 += t1; A2 += t2; A3 += t3; }

#define ACCM2(u, A0, A1, A2, A3) {                                        \
  f2_t t0, t1, t2, t3;                                                    \
  t0.x = asf((u).x << 16); t0.y = asf((u).x & 0xffff0000u);               \
  t1.x = asf((u).y << 16); t1.y = asf((u).y & 0xffff0000u);               \
  t2.x = asf((u).z << 16); t2.y = asf((u).z & 0xffff0000u);               \
  t3.x = asf((u).w << 16); t3.y = asf((u).w & 0xffff0000u);               \
  A0 += FMAX2Z(t0); A1 += FMAX2Z(t1); A2 += FMAX2Z(t2); A3 += FMAX2Z(t3); }

__global__ void spmm_plain(const int* __restrict__ row_ptr, const int* __restrict__ cols_s,
                           const u16* __restrict__ xin, u16* __restrict__ yout) {
  int bb = blockIdx.x;
  int b = (bb >= 10000) ? 1 : 0;
  int row = (bb - b * 10000) * 4 + (threadIdx.x >> 6);
  int l = threadIdx.x & 63;
  int g = l >> 4, sl = l & 15;
  int s = row_ptr[row], e = row_ptr[row + 1];
  const uint4* X = (const uint4*)xin + (size_t)b * 640000 + sl;
  f2_t A0 = {0.f, 0.f}, A1 = {0.f, 0.f}, A2 = {0.f, 0.f}, A3 = {0.f, 0.f};
  int i = s;
  for (; i + 7 < e; i += 8) {
    int c0 = cols_s[i + g], c1 = cols_s[i + 4 + g];
    uint4 u0 = X[(size_t)c0 * 16];
    uint4 u1 = X[(size_t)c1 * 16];
    ACCP2(u0, A0, A1, A2, A3);
    ACCP2(u1, A0, A1, A2, A3);
  }
  for (; i + 3 < e; i += 4) {
    int c = cols_s[i + g];
    uint4 u = X[(size_t)c * 16];
    ACCP2(u, A0, A1, A2, A3);
  }
  if (i + g < e) {
    int c = cols_s[i + g];
    uint4 u = X[(size_t)c * 16];
    ACCP2(u, A0, A1, A2, A3);
  }
  A0.x += __shfl_xor(A0.x, 16); A0.y += __shfl_xor(A0.y, 16);
  A1.x += __shfl_xor(A1.x, 16); A1.y += __shfl_xor(A1.y, 16);
  A2.x += __shfl_xor(A2.x, 16); A2.y += __shfl_xor(A2.y, 16);
  A3.x += __shfl_xor(A3.x, 16); A3.y += __shfl_xor(A3.y, 16);
  A0.x += __shfl_xor(A0.x, 32); A0.y += __shfl_xor(A0.y, 32);
  A1.x += __shfl_xor(A1.x, 32); A1.y += __shfl_xor(A1.y, 32);
  A2.x += __shfl_xor(A2.x, 32); A2.y += __shfl_xor(A2.y, 32);
  A3.x += __shfl_xor(A3.x, 32); A3.y += __shfl_xor(A3.y, 32);
  float sc = (e > s) ? 1.f / (float)(e - s) : 0.f;
  if (g == 0) {
    uint4 o;
    o.x = pack2(A0.x * sc, A0.y * sc);
    o.y = pack2(A1.x * sc, A1.y * sc);
    o.z = pack2(A2.x * sc, A2.y * sc);
    o.w = pack2(A3.x * sc, A3.y * sc);
    *((uint4*)yout + (size_t)b * 640000 + (size_t)row * 16 + sl) = o;
  }
}

__global__ void spmm_relu(const int* __restrict__ row_ptr, const int* __restrict__ cols_s,
                          const u16* __restrict__ xin, u16* __restrict__ yout) {
  int bb = blockIdx.x;
  int b = (bb >= 10000) ? 1 : 0;
  int row = (bb - b * 10000) * 4 + (threadIdx.x >> 6);
  int l = threadIdx.x & 63;
  int g = l >> 4, sl = l & 15;
  int s = row_ptr[row], e = row_ptr[row + 1];
  const uint4* X = (const uint4*)xin + (size_t)b * 640000 + sl;
  f2_t A0 = {0.f, 0.f}, A1 = {0.f, 0.f}, A2 = {0.f, 0.f}, A3 = {0.f, 0.f};
  int i = s;
  for (; i + 7 < e; i += 8) {
    int c0 = cols_s[i + g], c1 = cols_s[i + 4 + g];
    uint4 u0 = X[(size_t)c0 * 16];
    uint4 u1 = X[(size_t)c1 * 16];
    ACCM2(u0, A0, A1, A2, A3);
    ACCM2(u1, A0, A1, A2, A3);
  }
  for (; i + 3 < e; i += 4) {
    int c = cols_s[i + g];
    uint4 u = X[(size_t)c * 16];
    ACCM2(u, A0, A1, A2, A3);
  }
  if (i + g < e) {
    int c = cols_s[i + g];
    uint4 u = X[(size_t)c * 16];
    ACCM2(u, A0, A1, A2, A3);
  }
  A0.x += __shfl_xor(A0.x, 16); A0.y += __shfl_xor(A0.y, 16);
  A1.x += __shfl_xor(A1.x, 16); A1.y += __shfl_xor(A1.y, 16);
  A2.x += __shfl_xor(A2.x, 16); A2.y += __shfl_xor(A2.y, 16);
  A3.x += __shfl_xor(A3.x, 16); A3.y += __shfl_xor(A3.y, 16);
  A0.x += __shfl_xor(A0.x, 32); A0.y += __shfl_xor(A0.y, 32);
  A1.x += __shfl_xor(A1.x, 32); A1.y += __shfl_xor(A1.y, 32);
  A2.x += __shfl_xor(A2.x, 32); A2.y += __shfl_xor(A2.y, 32);
  A3.x += __shfl_xor(A3.x, 32); A3.y += __shfl_xor(A3.y, 32);
  float sc = (e > s) ? 1.f / (float)(e - s) : 0.f;
  if (g == 0) {
    uint4 o;
    o.x = pack2(A0.x * sc, A0.y * sc);
    o.y = pack2(A1.x * sc, A1.y * sc);
    o.z = pack2(A2.x * sc, A2.y * sc);
    o.w = pack2(A3.x * sc, A3.y * sc);
    *((uint4*)yout + (size_t)b * 640000 + (size_t)row * 16 + sl) = o;
  }
}

// ---------------- fused gconv GEMM: [fin(rin) | y] (M x 256) @ WtCat[g]^T (256 x 128) + bias ----
// FROZEN TEXT (r17/r26 restructures both failed threshold with no locatable bug).
// MODE 0: A-half = relu(rin) in staging; rout = relu(acc+bias)                 (rin = xb)
// MODE 1: A-half = rin as-is (rB); xb += acc+bias, write xb only
// MODE 2: MODE 1 + fused zproj (zf/zs from fp32 xb+dx), NO xb write (dead after)
#define TS 136                                   // tile row stride (u16); 272 B, 16B-aligned
template <int MODE>
__global__ __launch_bounds__(256, 4) void gemm_kernel(
    const u16* __restrict__ rin, const u16* __restrict__ yin,
    const u16* __restrict__ WtCat, const float* __restrict__ biasCat, int g,
    u16* __restrict__ rout, u16* __restrict__ xresid,
    float4* __restrict__ zf4, float4* __restrict__ zs4,
    const float* __restrict__ Wfo, const float* __restrict__ Wso,
    const float* __restrict__ bfo, const float* __restrict__ bso) {
  __shared__ __align__(16) u16 lds[18432];       // 36,864 B: ldsA[0..9215], ldsW[9216..]; epi tile 128*TS
  u16* ldsW = lds + 9216;
  int tid = threadIdx.x;
  int m0 = blockIdx.x * 128;
  int li = tid & 15, q = (tid >> 4) & 3, wv = tid >> 6;
  int wmo = (wv >> 1) * 64, wno = (wv & 1) * 64;

  f4_t acc[4][4];
#pragma unroll
  for (int i = 0; i < 4; ++i)
#pragma unroll
    for (int j = 0; j < 4; ++j) acc[i][j] = (f4_t){0.f, 0.f, 0.f, 0.f};

  const u16* Wsrc = WtCat + (size_t)g * 32768;

  for (int kb = 0; kb < 256; kb += 64) {
    __syncthreads();
    const u16* srcA = (kb < 128) ? (rin + kb) : (yin + (kb - 128));
#pragma unroll
    for (int p2 = 0; p2 < 4; ++p2) {
      int idx = p2 * 256 + tid;                  // 0..1023
      int row = idx >> 3, seg = idx & 7;
      uint4 va = *reinterpret_cast<const uint4*>(srcA + (size_t)(m0 + row) * 128 + seg * 8);
      if (MODE == 0 && kb < 128) {               // relu-on-read of xb
        va.x = relu2(va.x); va.y = relu2(va.y); va.z = relu2(va.z); va.w = relu2(va.w);
      }
      *reinterpret_cast<uint4*>(&lds[row * 72 + seg * 8]) = va;
      uint4 vw = *reinterpret_cast<const uint4*>(Wsrc + (size_t)row * 256 + kb + seg * 8);
      *reinterpret_cast<uint4*>(&ldsW[row * 72 + seg * 8]) = vw;
    }
    __syncthreads();
#pragma unroll
    for (int kk = 0; kk < 64; kk += 32) {
      bf8_t af[4], wf[4];
#pragma unroll
      for (int t = 0; t < 4; ++t)
        af[t] = __builtin_bit_cast(bf8_t,
            *reinterpret_cast<const uint4*>(&lds[(wmo + t * 16 + li) * 72 + kk + q * 8]));
#pragma unroll
      for (int t = 0; t < 4; ++t)
        wf[t] = __builtin_bit_cast(bf8_t,
            *reinterpret_cast<const uint4*>(&ldsW[(wno + t * 16 + li) * 72 + kk + q * 8]));
#pragma unroll
      for (int i = 0; i < 4; ++i)
#pragma unroll
        for (int j = 0; j < 4; ++j)
          acc[i][j] = __builtin_amdgcn_mfma_f32_16x16x32_bf16(af[i], wf[j], acc[i][j], 0, 0, 0);
    }
  }

  float bias[4];
#pragma unroll
  for (int j = 0; j < 4; ++j) bias[j] = biasCat[g * 128 + wno + j * 16 + li];

  __syncthreads();                               // LDS readers done; reuse as epilogue tile
#pragma unroll
  for (int i = 0; i < 4; ++i)
#pragma unroll
    for (int j = 0; j < 4; ++j)
#pragma unroll
      for (int r2 = 0; r2 < 4; ++r2) {
        int m = wmo + i * 16 + q * 4 + r2;
        int col = wno + j * 16 + li;
        lds[m * TS + col] = f2bf(acc[i][j][r2] + bias[j]);
      }
  __syncthreads();

  // epilogue weights for MODE2 (chunk-invariant: ch = (tid&15)*8 .. +7)
  float wzf[8][3], wzs[8][3];
  if (MODE == 2) {
    int chb = (tid & 15) * 8;
#pragma unroll
    for (int c = 0; c < 8; ++c)
#pragma unroll
      for (int d = 0; d < 3; ++d) {
        wzf[c][d] = Wfo[(chb + c) * 3 + d];
        wzs[c][d] = Wso[(chb + c) * 3 + d];
      }
  }

  // coalesced IO: 2048 uint4 chunks (row = idx>>4, 8-col chunk = idx&15)
#pragma unroll
  for (int p2 = 0; p2 < 8; ++p2) {
    int idx = p2 * 256 + tid;
    int row = idx >> 4, ch = idx & 15;
    uint4 cv = *reinterpret_cast<const uint4*>(&lds[row * TS + ch * 8]);
    size_t gid = (size_t)(m0 + row) * 16 + ch;
    if (MODE == 0) {
      uint4 o;
      o.x = relu2(cv.x); o.y = relu2(cv.y); o.z = relu2(cv.z); o.w = relu2(cv.w);
      ((uint4*)rout)[gid] = o;
    } else if (MODE == 1) {
      uint4 xv = ((const uint4*)xresid)[gid];
      uint4 nx;
      float x0, x1;
      x0 = lo2f(xv.x) + lo2f(cv.x); x1 = hi2f(xv.x) + hi2f(cv.x); nx.x = pack2(x0, x1);
      x0 = lo2f(xv.y) + lo2f(cv.y); x1 = hi2f(xv.y) + hi2f(cv.y); nx.y = pack2(x0, x1);
      x0 = lo2f(xv.z) + lo2f(cv.z); x1 = hi2f(xv.z) + hi2f(cv.z); nx.z = pack2(x0, x1);
      x0 = lo2f(xv.w) + lo2f(cv.w); x1 = hi2f(xv.w) + hi2f(cv.w); nx.w = pack2(x0, x1);
      ((uint4*)xresid)[gid] = nx;
    } else {                                     // MODE 2: fused zproj, no xb write
      uint4 xv = ((const uint4*)xresid)[gid];
      float zf0 = 0.f, zf1 = 0.f, zf2 = 0.f, zs0 = 0.f, zs1 = 0.f, zs2 = 0.f;
#pragma unroll
      for (int q2 = 0; q2 < 4; ++q2) {
        u32 xu = ((const u32*)&xv)[q2], cu = ((const u32*)&cv)[q2];
        float r0 = fmaxf(lo2f(xu) + lo2f(cu), 0.f);
        float r1 = fmaxf(hi2f(xu) + hi2f(cu), 0.f);
        int c = 2 * q2;
        zf0 += r0 * wzf[c][0] + r1 * wzf[c + 1][0];
        zf1 += r0 * wzf[c][1] + r1 * wzf[c + 1][1];
        zf2 += r0 * wzf[c][2] + r1 * wzf[c + 1][2];
        zs0 += r0 * wzs[c][0] + r1 * wzs[c + 1][0];
        zs1 += r0 * wzs[c][1] + r1 * wzs[c + 1][1];
        zs2 += r0 * wzs[c][2] + r1 * wzs[c + 1][2];
      }
#pragma unroll
      for (int off = 1; off < 16; off <<= 1) {
        zf0 += __shfl_xor(zf0, off); zf1 += __shfl_xor(zf1, off); zf2 += __shfl_xor(zf2, off);
        zs0 += __shfl_xor(zs0, off); zs1 += __shfl_xor(zs1, off); zs2 += __shfl_xor(zs2, off);
      }
      if ((tid & 15) == 0) {
        int m = m0 + row;
        zf4[m] = make_float4(zf0, zf1, zf2, 0.f);
        zs4[m] = make_float4(zs0 + bso[0] + bfo[0], zs1 + bso[1] + bfo[1],
                             zs2 + bso[2] + bfo[2], 0.f);
      }
    }
  }
}

// ---------------- 3-channel spmm + add ----------------
__global__ void spmm3_kernel(const int* __restrict__ row_ptr, const int* __restrict__ cols_s,
                             const float4* __restrict__ zf4, const float4* __restrict__ zs4,
                             float* __restrict__ out) {
  int idx = blockIdx.x * 256 + threadIdx.x;
  if (idx >= BN) return;
  int b = (idx >= N_NODES) ? 1 : 0;
  int r = idx - b * N_NODES;
  int s = row_ptr[r], e = row_ptr[r + 1];
  const float4* Z = zf4 + (size_t)b * N_NODES;
  float a0 = 0.f, a1 = 0.f, a2 = 0.f;
  for (int i = s; i < e; ++i) {
    float4 z = Z[cols_s[i]];
    a0 += z.x; a1 += z.y; a2 += z.z;
  }
  float sc = (e > s) ? 1.f / (float)(e - s) : 0.f;
  float4 zs = zs4[idx];
  out[idx * 3 + 0] = zs.x + a0 * sc;
  out[idx * 3 + 1] = zs.y + a1 * sc;
  out[idx * 3 + 2] = zs.z + a2 * sc;
}

extern "C" void kernel_launch(void* const* d_in, const int* in_sizes, int n_in,
                              void* d_out, int out_size, void* d_ws, size_t ws_size,
                              hipStream_t stream) {
  float* out = (float*)d_out;
  int fill_grid = (out_size + 255) / 256;

  const int exp_sizes[14] = {240000, 640000, 640000, 640000, 384, 128,
                             65536, 512, 65536, 512, 384, 3, 384, 3};
  bool sizes_ok = (n_in == 14);
  if (sizes_ok) for (int i = 0; i < 14; ++i) if (in_sizes[i] != exp_sizes[i]) sizes_ok = false;
  if (!sizes_ok) {
    fill_kernel<<<fill_grid, 256, 0, stream>>>(out, out_size, 1.0f);
    return;
  }

  const size_t NEED = (size_t)4 * BN * 128 * 2 + (size_t)N_EDGES * 4 + 160016 + 160000 + 1024 + 262144 + 2048;
  if (ws_size < NEED) {
    fill_kernel<<<fill_grid, 256, 0, stream>>>(out, out_size, 0.0f);
    return;
  }

  const float* p      = (const float*)d_in[0];
  const int*   erows  = (const int*)d_in[2];
  const int*   ecols  = (const int*)d_in[3];
  const float* W_init = (const float*)d_in[4];
  const float* b_init = (const float*)d_in[5];
  const float* Wf_b   = (const float*)d_in[6];
  const float* bf_b   = (const float*)d_in[7];
  const float* Ws_b   = (const float*)d_in[8];
  const float* bs_b   = (const float*)d_in[9];
  const float* Wf_o   = (const float*)d_in[10];
  const float* bf_o   = (const float*)d_in[11];
  const float* Ws_o   = (const float*)d_in[12];
  const float* bs_o   = (const float*)d_in[13];

  char* w = (char*)d_ws;
  char*  zbuf     = w;         w += (size_t)BN * 128 * 2;       // holds zf4/zs4
  u16*   rB       = (u16*)w;   w += (size_t)BN * 128 * 2;
  u16*   y        = (u16*)w;   w += (size_t)BN * 128 * 2;
  u16*   xb       = (u16*)w;   w += (size_t)BN * 128 * 2;
  int*   cols_s   = (int*)w;   w += (size_t)N_EDGES * 4;
  int*   row_ptr  = (int*)w;   w += 160016;
  int*   cnt      = (int*)w;   w += 160000;
  int*   blocksum = (int*)w;   w += 1024;
  u16*   WtCat    = (u16*)w;   w += 4 * 128 * 256 * 2;
  float* biasCat  = (float*)w; w += 4 * 128 * 4;

  float4* zf4 = (float4*)zbuf;                                  // 1,280,000 B
  float4* zs4 = (float4*)(zbuf + 1280000);                      // 1,280,000 B

  const int NBLK = (N_NODES + 255) / 256;                       // 157

  hipMemsetAsync(cnt, 0, N_NODES * 4, stream);
  initw_kernel<<<23012, 256, 0, stream>>>(p, W_init, b_init, xb,
                                          Wf_b, Ws_b, bf_b, bs_b, WtCat, biasCat,
                                          erows, cnt);
  scan1_kernel<<<NBLK, 256, 0, stream>>>(cnt, row_ptr, blocksum);
  scan2_kernel<<<1, 256, 0, stream>>>(blocksum, row_ptr, NBLK);
  scan3_kernel<<<NBLK, 256, 0, stream>>>(row_ptr, blocksum, cnt);
  scatter_kernel<<<2500, 256, 0, stream>>>(erows, ecols, cnt, cols_s);
  sortcols_kernel<<<10000, 256, 0, stream>>>(row_ptr, cols_s);

  for (int blk = 0; blk < 2; ++blk) {
    spmm_relu<<<20000, 256, 0, stream>>>(row_ptr, cols_s, xb, y);
    gemm_kernel<0><<<625, 256, 0, stream>>>(xb, y, WtCat, biasCat, 2 * blk, rB, nullptr,
                                            nullptr, nullptr, nullptr, nullptr, nullptr, nullptr);
    spmm_plain<<<20000, 256, 0, stream>>>(row_ptr, cols_s, rB, y);
    if (blk == 0)
      gemm_kernel<1><<<625, 256, 0, stream>>>(rB, y, WtCat, biasCat, 1, nullptr, xb,
                                              nullptr, nullptr, nullptr, nullptr, nullptr, nullptr);
    else
      gemm_kernel<2><<<625, 256, 0, stream>>>(rB, y, WtCat, biasCat, 3, nullptr, xb,
                                              zf4, zs4, Wf_o, Ws_o, bf_o, bs_o);
  }
  spmm3_kernel<<<(BN + 255) / 256, 256, 0, stream>>>(row_ptr, cols_s, zf4, zs4, out);
}

// Round 14
// 431.362 us; speedup vs baseline: 1.0112x; 1.0112x over previous
//
#include <hip/hip_runtime.h>

// GCNDecoder: B=2, N=40000, HID=128, E=640000, IN=3, OUT=3. Float tensors f32; indices int32.
//
// Round 28 vs round 27 (=r25, 436.2 us, PASSED):
//   - spmm index-prefetch rotation: load iter i+1's cols_s indices BEFORE consuming
//     iter i's gathered x rows (wave-uniform guard; s,e uniform per wave). The fp
//     accumulation sequence is UNCHANGED (safe class: r19/r25 both passed) — only
//     load issue order shifts. Attacks the one untested axis: the serial
//     idx-load -> x-gather dependency chain (~200 cyc exposed per 8-edge iter).
//   - everything else r27-verbatim (initw/gemm/spmm3 FROZEN; 3/3 value-path
//     restructures failed threshold).

typedef unsigned short u16;
typedef unsigned int   u32;
typedef __bf16 bf8_t __attribute__((ext_vector_type(8)));
typedef float  f4_t  __attribute__((ext_vector_type(4)));
typedef float  f2_t  __attribute__((ext_vector_type(2)));

#define N_NODES 40000
#define N_EDGES 640000
#define BN      80000            // BATCH * N_NODES

__device__ __forceinline__ float bf2f(u16 u) {
  union { u32 i; float f; } v; v.i = ((u32)u) << 16; return v.f;
}
__device__ __forceinline__ u16 f2bf(float f) {
  union { float f; u32 i; } v; v.f = f;
  u32 i = v.i;
  return (u16)((i + 0x7FFFu + ((i >> 16) & 1u)) >> 16);   // RNE
}
__device__ __forceinline__ float asf(u32 i) {
  union { u32 u; float f; } v; v.u = i; return v.f;
}
__device__ __forceinline__ u32 pack2(float a, float b) {
  return (u32)f2bf(a) | ((u32)f2bf(b) << 16);
}
__device__ __forceinline__ float lo2f(u32 v) { return asf(v << 16); }
__device__ __forceinline__ float hi2f(u32 v) { return asf(v & 0xffff0000u); }
__device__ __forceinline__ u32 relu2(u32 v) {     // zero out negative bf16 halves (packed)
  u32 r = v;
  if (r & 0x8000u)     r &= 0xffff0000u;
  if (r & 0x80000000u) r &= 0x0000ffffu;
  return r;
}

#if defined(__has_builtin)
#if __has_builtin(__builtin_elementwise_max)
#define FMAX2Z(a) __builtin_elementwise_max((a), (f2_t){0.f, 0.f})
#endif
#endif
#ifndef FMAX2Z
#define FMAX2Z(a) ((f2_t){fmaxf((a).x, 0.f), fmaxf((a).y, 0.f)})
#endif

__global__ void fill_kernel(float* __restrict__ out, int n, float v) {
  int i = blockIdx.x * 256 + threadIdx.x;
  if (i < n) out[i] = v;
}

// ---------------- CSR scan (3-phase) + scatter ----------------
__global__ void scan1_kernel(const int* __restrict__ cnt, int* __restrict__ row_ptr,
                             int* __restrict__ blocksum) {
  __shared__ int sm[256];
  int t = threadIdx.x;
  int row = blockIdx.x * 256 + t;
  int v = (row < N_NODES) ? cnt[row] : 0;
  sm[t] = v; __syncthreads();
  for (int off = 1; off < 256; off <<= 1) {
    int u = (t >= off) ? sm[t - off] : 0;
    __syncthreads();
    sm[t] += u;
    __syncthreads();
  }
  if (row < N_NODES) row_ptr[row] = sm[t] - v;
  if (t == 255) blocksum[blockIdx.x] = sm[255];
}

__global__ void scan2_kernel(int* __restrict__ blocksum, int* __restrict__ row_ptr, int nblk) {
  __shared__ int sm[256];
  int t = threadIdx.x;
  int v = (t < nblk) ? blocksum[t] : 0;
  sm[t] = v; __syncthreads();
  for (int off = 1; off < 256; off <<= 1) {
    int u = (t >= off) ? sm[t - off] : 0;
    __syncthreads();
    sm[t] += u;
    __syncthreads();
  }
  if (t < nblk) blocksum[t] = sm[t] - v;
  if (t == 255) row_ptr[N_NODES] = sm[255];
}

__global__ void scan3_kernel(int* __restrict__ row_ptr, const int* __restrict__ blocksum,
                             int* __restrict__ cnt) {
  int row = blockIdx.x * 256 + threadIdx.x;
  if (row < N_NODES) {
    int rp = row_ptr[row] + blocksum[blockIdx.x];
    row_ptr[row] = rp;
    cnt[row] = rp;
  }
}

__global__ void scatter_kernel(const int* __restrict__ rows, const int* __restrict__ cols,
                               int* __restrict__ cur, int* __restrict__ cols_s) {
  int e = blockIdx.x * 256 + threadIdx.x;
  if (e < N_EDGES) {
    int r = rows[e];
    int pos = atomicAdd(&cur[r], 1);
    cols_s[pos] = cols[e];
  }
}

// ---------------- canonicalize CSR segment order (bit-determinism across calls) ----------
__global__ void sortcols_kernel(const int* __restrict__ row_ptr, int* __restrict__ cols_s) {
  int row = blockIdx.x * 4 + (threadIdx.x >> 6);   // grid 10000 * 4 waves = 40000 rows
  int l = threadIdx.x & 63;
  int s = row_ptr[row], e = row_ptr[row + 1];
  int deg = e - s;
  if (deg <= 1) return;                            // wave-uniform branch
  if (deg <= 64) {
    int v = (l < deg) ? cols_s[s + l] : 0x7fffffff;
#pragma unroll
    for (int k = 2; k <= 64; k <<= 1) {
#pragma unroll
      for (int j = k >> 1; j >= 1; j >>= 1) {
        int p = __shfl_xor(v, j);
        bool up = ((l & k) == 0);
        bool keepmin = (((l & j) == 0) == up);
        int mn = v < p ? v : p;
        int mx = v < p ? p : v;
        v = keepmin ? mn : mx;
      }
    }
    if (l < deg) cols_s[s + l] = v;
  } else if (l == 0) {                             // ultra-rare fallback: serial insertion
    for (int i = s + 1; i < e; ++i) {
      int key = cols_s[i];
      int j = i - 1;
      while (j >= s && cols_s[j] > key) { cols_s[j + 1] = cols_s[j]; --j; }
      cols_s[j + 1] = key;
    }
  }
}

// ---------------- merged: xb init (20000) + wprep (512) + hist (2500) ----------------
// FROZEN TEXT (r9 experiment: restructuring this broke post-timing determinism).
__global__ void initw_kernel(const float* __restrict__ p, const float* __restrict__ W,
                             const float* __restrict__ bias, u16* __restrict__ xb,
                             const float* __restrict__ Wf_b, const float* __restrict__ Ws_b,
                             const float* __restrict__ bf_b, const float* __restrict__ bs_b,
                             u16* __restrict__ WtCat, float* __restrict__ biasCat,
                             const int* __restrict__ erows, int* __restrict__ cnt) {
  if (blockIdx.x >= 20512) {                     // hist part: 2500 blocks
    int e = (blockIdx.x - 20512) * 256 + threadIdx.x;
    if (e < N_EDGES) atomicAdd(&cnt[erows[e]], 1);
    return;
  }
  if (blockIdx.x >= 20000) {                     // wprep part: 512 blocks
    int idx = (blockIdx.x - 20000) * 256 + threadIdx.x;   // 4*128*256 = 131072
    int g = idx >> 15, rem = idx & 32767;
    int h = rem >> 8, k = rem & 255;
    float v = (k < 128) ? Ws_b[(g * 128 + k) * 128 + h]
                        : Wf_b[(g * 128 + (k - 128)) * 128 + h];
    WtCat[idx] = f2bf(v);
    if (k == 0) biasCat[g * 128 + h] = bs_b[g * 128 + h] + bf_b[g * 128 + h];
    return;
  }
  int idx = blockIdx.x * 256 + threadIdx.x;      // BN*64 = 5,120,000
  int row = idx >> 6;
  int h = (idx & 63) * 2;
  float p0 = p[row * 3], p1 = p[row * 3 + 1], p2 = p[row * 3 + 2];
  float s0 = p0 * W[h]     + p1 * W[128 + h]     + p2 * W[256 + h]     + bias[h];
  float s1 = p0 * W[h + 1] + p1 * W[128 + h + 1] + p2 * W[256 + h + 1] + bias[h + 1];
  ((u32*)xb)[(size_t)row * 64 + (h >> 1)] = pack2(s0, s1);
}

// ---------------- gather SPMM, batch-split, pk accumulators + index prefetch ----------
// r28: rotate cols_s loads one iteration ahead (wave-uniform guard). fp accumulation
// sequence identical to r25 -> bit-identical output.
#define ACCP2(u, A0, A1, A2, A3) {                                        \
  f2_t t0, t1, t2, t3;                                                    \
  t0.x = asf((u).x << 16); t0.y = asf((u).x & 0xffff0000u);               \
  t1.x = asf((u).y << 16); t1.y = asf((u).y & 0xffff0000u);               \
  t2.x = asf((u).z << 16); t2.y = asf((u).z & 0xffff0000u);               \
  t3.x = asf((u).w << 16); t3.y = asf((u).w & 0xffff0000u);               \
  A0 += t0; A1 += t1; A2 += t2; A3 += t3; }

#define ACCM2(u, A0, A1, A2, A3) {                                        \
  f2_t t0, t1, t2, t3;                                                    \
  t0.x = asf((u).x << 16); t0.y = asf((u).x & 0xffff0000u);               \
  t1.x = asf((u).y << 16); t1.y = asf((u).y & 0xffff0000u);               \
  t2.x = asf((u).z << 16); t2.y = asf((u).z & 0xffff0000u);               \
  t3.x = asf((u).w << 16); t3.y = asf((u).w & 0xffff0000u);               \
  A0 += FMAX2Z(t0); A1 += FMAX2Z(t1); A2 += FMAX2Z(t2); A3 += FMAX2Z(t3); }

__global__ void spmm_plain(const int* __restrict__ row_ptr, const int* __restrict__ cols_s,
                           const u16* __restrict__ xin, u16* __restrict__ yout) {
  int bb = blockIdx.x;
  int b = (bb >= 10000) ? 1 : 0;
  int row = (bb - b * 10000) * 4 + (threadIdx.x >> 6);
  int l = threadIdx.x & 63;
  int g = l >> 4, sl = l & 15;
  int s = row_ptr[row], e = row_ptr[row + 1];
  const uint4* X = (const uint4*)xin + (size_t)b * 640000 + sl;
  f2_t A0 = {0.f, 0.f}, A1 = {0.f, 0.f}, A2 = {0.f, 0.f}, A3 = {0.f, 0.f};
  int i = s;
  if (i + 7 < e) {
    int c0 = cols_s[i + g], c1 = cols_s[i + 4 + g];
    while (true) {
      uint4 u0 = X[(size_t)c0 * 16];
      uint4 u1 = X[(size_t)c1 * 16];
      int ni = i + 8;
      int n0 = 0, n1 = 0;
      bool more = (ni + 7 < e);                  // wave-uniform
      if (more) { n0 = cols_s[ni + g]; n1 = cols_s[ni + 4 + g]; }
      ACCP2(u0, A0, A1, A2, A3);
      ACCP2(u1, A0, A1, A2, A3);
      i = ni;
      if (!more) break;
      c0 = n0; c1 = n1;
    }
  }
  for (; i + 3 < e; i += 4) {
    int c = cols_s[i + g];
    uint4 u = X[(size_t)c * 16];
    ACCP2(u, A0, A1, A2, A3);
  }
  if (i + g < e) {
    int c = cols_s[i + g];
    uint4 u = X[(size_t)c * 16];
    ACCP2(u, A0, A1, A2, A3);
  }
  A0.x += __shfl_xor(A0.x, 16); A0.y += __shfl_xor(A0.y, 16);
  A1.x += __shfl_xor(A1.x, 16); A1.y += __shfl_xor(A1.y, 16);
  A2.x += __shfl_xor(A2.x, 16); A2.y += __shfl_xor(A2.y, 16);
  A3.x += __shfl_xor(A3.x, 16); A3.y += __shfl_xor(A3.y, 16);
  A0.x += __shfl_xor(A0.x, 32); A0.y += __shfl_xor(A0.y, 32);
  A1.x += __shfl_xor(A1.x, 32); A1.y += __shfl_xor(A1.y, 32);
  A2.x += __shfl_xor(A2.x, 32); A2.y += __shfl_xor(A2.y, 32);
  A3.x += __shfl_xor(A3.x, 32); A3.y += __shfl_xor(A3.y, 32);
  float sc = (e > s) ? 1.f / (float)(e - s) : 0.f;
  if (g == 0) {
    uint4 o;
    o.x = pack2(A0.x * sc, A0.y * sc);
    o.y = pack2(A1.x * sc, A1.y * sc);
    o.z = pack2(A2.x * sc, A2.y * sc);
    o.w = pack2(A3.x * sc, A3.y * sc);
    *((uint4*)yout + (size_t)b * 640000 + (size_t)row * 16 + sl) = o;
  }
}

__global__ void spmm_relu(const int* __restrict__ row_ptr, const int* __restrict__ cols_s,
                          const u16* __restrict__ xin, u16* __restrict__ yout) {
  int bb = blockIdx.x;
  int b = (bb >= 10000) ? 1 : 0;
  int row = (bb - b * 10000) * 4 + (threadIdx.x >> 6);
  int l = threadIdx.x & 63;
  int g = l >> 4, sl = l & 15;
  int s = row_ptr[row], e = row_ptr[row + 1];
  const uint4* X = (const uint4*)xin + (size_t)b * 640000 + sl;
  f2_t A0 = {0.f, 0.f}, A1 = {0.f, 0.f}, A2 = {0.f, 0.f}, A3 = {0.f, 0.f};
  int i = s;
  if (i + 7 < e) {
    int c0 = cols_s[i + g], c1 = cols_s[i + 4 + g];
    while (true) {
      uint4 u0 = X[(size_t)c0 * 16];
      uint4 u1 = X[(size_t)c1 * 16];
      int ni = i + 8;
      int n0 = 0, n1 = 0;
      bool more = (ni + 7 < e);                  // wave-uniform
      if (more) { n0 = cols_s[ni + g]; n1 = cols_s[ni + 4 + g]; }
      ACCM2(u0, A0, A1, A2, A3);
      ACCM2(u1, A0, A1, A2, A3);
      i = ni;
      if (!more) break;
      c0 = n0; c1 = n1;
    }
  }
  for (; i + 3 < e; i += 4) {
    int c = cols_s[i + g];
    uint4 u = X[(size_t)c * 16];
    ACCM2(u, A0, A1, A2, A3);
  }
  if (i + g < e) {
    int c = cols_s[i + g];
    uint4 u = X[(size_t)c * 16];
    ACCM2(u, A0, A1, A2, A3);
  }
  A0.x += __shfl_xor(A0.x, 16); A0.y += __shfl_xor(A0.y, 16);
  A1.x += __shfl_xor(A1.x, 16); A1.y += __shfl_xor(A1.y, 16);
  A2.x += __shfl_xor(A2.x, 16); A2.y += __shfl_xor(A2.y, 16);
  A3.x += __shfl_xor(A3.x, 16); A3.y += __shfl_xor(A3.y, 16);
  A0.x += __shfl_xor(A0.x, 32); A0.y += __shfl_xor(A0.y, 32);
  A1.x += __shfl_xor(A1.x, 32); A1.y += __shfl_xor(A1.y, 32);
  A2.x += __shfl_xor(A2.x, 32); A2.y += __shfl_xor(A2.y, 32);
  A3.x += __shfl_xor(A3.x, 32); A3.y += __shfl_xor(A3.y, 32);
  float sc = (e > s) ? 1.f / (float)(e - s) : 0.f;
  if (g == 0) {
    uint4 o;
    o.x = pack2(A0.x * sc, A0.y * sc);
    o.y = pack2(A1.x * sc, A1.y * sc);
    o.z = pack2(A2.x * sc, A2.y * sc);
    o.w = pack2(A3.x * sc, A3.y * sc);
    *((uint4*)yout + (size_t)b * 640000 + (size_t)row * 16 + sl) = o;
  }
}

// ---------------- fused gconv GEMM: [fin(rin) | y] (M x 256) @ WtCat[g]^T (256 x 128) + bias ----
// FROZEN TEXT (r17/r26 restructures both failed threshold with no locatable bug).
// MODE 0: A-half = relu(rin) in staging; rout = relu(acc+bias)                 (rin = xb)
// MODE 1: A-half = rin as-is (rB); xb += acc+bias, write xb only
// MODE 2: MODE 1 + fused zproj (zf/zs from fp32 xb+dx), NO xb write (dead after)
#define TS 136                                   // tile row stride (u16); 272 B, 16B-aligned
template <int MODE>
__global__ __launch_bounds__(256, 4) void gemm_kernel(
    const u16* __restrict__ rin, const u16* __restrict__ yin,
    const u16* __restrict__ WtCat, const float* __restrict__ biasCat, int g,
    u16* __restrict__ rout, u16* __restrict__ xresid,
    float4* __restrict__ zf4, float4* __restrict__ zs4,
    const float* __restrict__ Wfo, const float* __restrict__ Wso,
    const float* __restrict__ bfo, const float* __restrict__ bso) {
  __shared__ __align__(16) u16 lds[18432];       // 36,864 B: ldsA[0..9215], ldsW[9216..]; epi tile 128*TS
  u16* ldsW = lds + 9216;
  int tid = threadIdx.x;
  int m0 = blockIdx.x * 128;
  int li = tid & 15, q = (tid >> 4) & 3, wv = tid >> 6;
  int wmo = (wv >> 1) * 64, wno = (wv & 1) * 64;

  f4_t acc[4][4];
#pragma unroll
  for (int i = 0; i < 4; ++i)
#pragma unroll
    for (int j = 0; j < 4; ++j) acc[i][j] = (f4_t){0.f, 0.f, 0.f, 0.f};

  const u16* Wsrc = WtCat + (size_t)g * 32768;

  for (int kb = 0; kb < 256; kb += 64) {
    __syncthreads();
    const u16* srcA = (kb < 128) ? (rin + kb) : (yin + (kb - 128));
#pragma unroll
    for (int p2 = 0; p2 < 4; ++p2) {
      int idx = p2 * 256 + tid;                  // 0..1023
      int row = idx >> 3, seg = idx & 7;
      uint4 va = *reinterpret_cast<const uint4*>(srcA + (size_t)(m0 + row) * 128 + seg * 8);
      if (MODE == 0 && kb < 128) {               // relu-on-read of xb
        va.x = relu2(va.x); va.y = relu2(va.y); va.z = relu2(va.z); va.w = relu2(va.w);
      }
      *reinterpret_cast<uint4*>(&lds[row * 72 + seg * 8]) = va;
      uint4 vw = *reinterpret_cast<const uint4*>(Wsrc + (size_t)row * 256 + kb + seg * 8);
      *reinterpret_cast<uint4*>(&ldsW[row * 72 + seg * 8]) = vw;
    }
    __syncthreads();
#pragma unroll
    for (int kk = 0; kk < 64; kk += 32) {
      bf8_t af[4], wf[4];
#pragma unroll
      for (int t = 0; t < 4; ++t)
        af[t] = __builtin_bit_cast(bf8_t,
            *reinterpret_cast<const uint4*>(&lds[(wmo + t * 16 + li) * 72 + kk + q * 8]));
#pragma unroll
      for (int t = 0; t < 4; ++t)
        wf[t] = __builtin_bit_cast(bf8_t,
            *reinterpret_cast<const uint4*>(&ldsW[(wno + t * 16 + li) * 72 + kk + q * 8]));
#pragma unroll
      for (int i = 0; i < 4; ++i)
#pragma unroll
        for (int j = 0; j < 4; ++j)
          acc[i][j] = __builtin_amdgcn_mfma_f32_16x16x32_bf16(af[i], wf[j], acc[i][j], 0, 0, 0);
    }
  }

  float bias[4];
#pragma unroll
  for (int j = 0; j < 4; ++j) bias[j] = biasCat[g * 128 + wno + j * 16 + li];

  __syncthreads();                               // LDS readers done; reuse as epilogue tile
#pragma unroll
  for (int i = 0; i < 4; ++i)
#pragma unroll
    for (int j = 0; j < 4; ++j)
#pragma unroll
      for (int r2 = 0; r2 < 4; ++r2) {
        int m = wmo + i * 16 + q * 4 + r2;
        int col = wno + j * 16 + li;
        lds[m * TS + col] = f2bf(acc[i][j][r2] + bias[j]);
      }
  __syncthreads();

  // epilogue weights for MODE2 (chunk-invariant: ch = (tid&15)*8 .. +7)
  float wzf[8][3], wzs[8][3];
  if (MODE == 2) {
    int chb = (tid & 15) * 8;
#pragma unroll
    for (int c = 0; c < 8; ++c)
#pragma unroll
      for (int d = 0; d < 3; ++d) {
        wzf[c][d] = Wfo[(chb + c) * 3 + d];
        wzs[c][d] = Wso[(chb + c) * 3 + d];
      }
  }

  // coalesced IO: 2048 uint4 chunks (row = idx>>4, 8-col chunk = idx&15)
#pragma unroll
  for (int p2 = 0; p2 < 8; ++p2) {
    int idx = p2 * 256 + tid;
    int row = idx >> 4, ch = idx & 15;
    uint4 cv = *reinterpret_cast<const uint4*>(&lds[row * TS + ch * 8]);
    size_t gid = (size_t)(m0 + row) * 16 + ch;
    if (MODE == 0) {
      uint4 o;
      o.x = relu2(cv.x); o.y = relu2(cv.y); o.z = relu2(cv.z); o.w = relu2(cv.w);
      ((uint4*)rout)[gid] = o;
    } else if (MODE == 1) {
      uint4 xv = ((const uint4*)xresid)[gid];
      uint4 nx;
      float x0, x1;
      x0 = lo2f(xv.x) + lo2f(cv.x); x1 = hi2f(xv.x) + hi2f(cv.x); nx.x = pack2(x0, x1);
      x0 = lo2f(xv.y) + lo2f(cv.y); x1 = hi2f(xv.y) + hi2f(cv.y); nx.y = pack2(x0, x1);
      x0 = lo2f(xv.z) + lo2f(cv.z); x1 = hi2f(xv.z) + hi2f(cv.z); nx.z = pack2(x0, x1);
      x0 = lo2f(xv.w) + lo2f(cv.w); x1 = hi2f(xv.w) + hi2f(cv.w); nx.w = pack2(x0, x1);
      ((uint4*)xresid)[gid] = nx;
    } else {                                     // MODE 2: fused zproj, no xb write
      uint4 xv = ((const uint4*)xresid)[gid];
      float zf0 = 0.f, zf1 = 0.f, zf2 = 0.f, zs0 = 0.f, zs1 = 0.f, zs2 = 0.f;
#pragma unroll
      for (int q2 = 0; q2 < 4; ++q2) {
        u32 xu = ((const u32*)&xv)[q2], cu = ((const u32*)&cv)[q2];
        float r0 = fmaxf(lo2f(xu) + lo2f(cu), 0.f);
        float r1 = fmaxf(hi2f(xu) + hi2f(cu), 0.f);
        int c = 2 * q2;
        zf0 += r0 * wzf[c][0] + r1 * wzf[c + 1][0];
        zf1 += r0 * wzf[c][1] + r1 * wzf[c + 1][1];
        zf2 += r0 * wzf[c][2] + r1 * wzf[c + 1][2];
        zs0 += r0 * wzs[c][0] + r1 * wzs[c + 1][0];
        zs1 += r0 * wzs[c][1] + r1 * wzs[c + 1][1];
        zs2 += r0 * wzs[c][2] + r1 * wzs[c + 1][2];
      }
#pragma unroll
      for (int off = 1; off < 16; off <<= 1) {
        zf0 += __shfl_xor(zf0, off); zf1 += __shfl_xor(zf1, off); zf2 += __shfl_xor(zf2, off);
        zs0 += __shfl_xor(zs0, off); zs1 += __shfl_xor(zs1, off); zs2 += __shfl_xor(zs2, off);
      }
      if ((tid & 15) == 0) {
        int m = m0 + row;
        zf4[m] = make_float4(zf0, zf1, zf2, 0.f);
        zs4[m] = make_float4(zs0 + bso[0] + bfo[0], zs1 + bso[1] + bfo[1],
                             zs2 + bso[2] + bfo[2], 0.f);
      }
    }
  }
}

// ---------------- 3-channel spmm + add ----------------
__global__ void spmm3_kernel(const int* __restrict__ row_ptr, const int* __restrict__ cols_s,
                             const float4* __restrict__ zf4, const float4* __restrict__ zs4,
                             float* __restrict__ out) {
  int idx = blockIdx.x * 256 + threadIdx.x;
  if (idx >= BN) return;
  int b = (idx >= N_NODES) ? 1 : 0;
  int r = idx - b * N_NODES;
  int s = row_ptr[r], e = row_ptr[r + 1];
  const float4* Z = zf4 + (size_t)b * N_NODES;
  float a0 = 0.f, a1 = 0.f, a2 = 0.f;
  for (int i = s; i < e; ++i) {
    float4 z = Z[cols_s[i]];
    a0 += z.x; a1 += z.y; a2 += z.z;
  }
  float sc = (e > s) ? 1.f / (float)(e - s) : 0.f;
  float4 zs = zs4[idx];
  out[idx * 3 + 0] = zs.x + a0 * sc;
  out[idx * 3 + 1] = zs.y + a1 * sc;
  out[idx * 3 + 2] = zs.z + a2 * sc;
}

extern "C" void kernel_launch(void* const* d_in, const int* in_sizes, int n_in,
                              void* d_out, int out_size, void* d_ws, size_t ws_size,
                              hipStream_t stream) {
  float* out = (float*)d_out;
  int fill_grid = (out_size + 255) / 256;

  const int exp_sizes[14] = {240000, 640000, 640000, 640000, 384, 128,
                             65536, 512, 65536, 512, 384, 3, 384, 3};
  bool sizes_ok = (n_in == 14);
  if (sizes_ok) for (int i = 0; i < 14; ++i) if (in_sizes[i] != exp_sizes[i]) sizes_ok = false;
  if (!sizes_ok) {
    fill_kernel<<<fill_grid, 256, 0, stream>>>(out, out_size, 1.0f);
    return;
  }

  const size_t NEED = (size_t)4 * BN * 128 * 2 + (size_t)N_EDGES * 4 + 160016 + 160000 + 1024 + 262144 + 2048;
  if (ws_size < NEED) {
    fill_kernel<<<fill_grid, 256, 0, stream>>>(out, out_size, 0.0f);
    return;
  }

  const float* p      = (const float*)d_in[0];
  const int*   erows  = (const int*)d_in[2];
  const int*   ecols  = (const int*)d_in[3];
  const float* W_init = (const float*)d_in[4];
  const float* b_init = (const float*)d_in[5];
  const float* Wf_b   = (const float*)d_in[6];
  const float* bf_b   = (const float*)d_in[7];
  const float* Ws_b   = (const float*)d_in[8];
  const float* bs_b   = (const float*)d_in[9];
  const float* Wf_o   = (const float*)d_in[10];
  const float* bf_o   = (const float*)d_in[11];
  const float* Ws_o   = (const float*)d_in[12];
  const float* bs_o   = (const float*)d_in[13];

  char* w = (char*)d_ws;
  char*  zbuf     = w;         w += (size_t)BN * 128 * 2;       // holds zf4/zs4
  u16*   rB       = (u16*)w;   w += (size_t)BN * 128 * 2;
  u16*   y        = (u16*)w;   w += (size_t)BN * 128 * 2;
  u16*   xb       = (u16*)w;   w += (size_t)BN * 128 * 2;
  int*   cols_s   = (int*)w;   w += (size_t)N_EDGES * 4;
  int*   row_ptr  = (int*)w;   w += 160016;
  int*   cnt      = (int*)w;   w += 160000;
  int*   blocksum = (int*)w;   w += 1024;
  u16*   WtCat    = (u16*)w;   w += 4 * 128 * 256 * 2;
  float* biasCat  = (float*)w; w += 4 * 128 * 4;

  float4* zf4 = (float4*)zbuf;                                  // 1,280,000 B
  float4* zs4 = (float4*)(zbuf + 1280000);                      // 1,280,000 B

  const int NBLK = (N_NODES + 255) / 256;                       // 157

  hipMemsetAsync(cnt, 0, N_NODES * 4, stream);
  initw_kernel<<<23012, 256, 0, stream>>>(p, W_init, b_init, xb,
                                          Wf_b, Ws_b, bf_b, bs_b, WtCat, biasCat,
                                          erows, cnt);
  scan1_kernel<<<NBLK, 256, 0, stream>>>(cnt, row_ptr, blocksum);
  scan2_kernel<<<1, 256, 0, stream>>>(blocksum, row_ptr, NBLK);
  scan3_kernel<<<NBLK, 256, 0, stream>>>(row_ptr, blocksum, cnt);
  scatter_kernel<<<2500, 256, 0, stream>>>(erows, ecols, cnt, cols_s);
  sortcols_kernel<<<10000, 256, 0, stream>>>(row_ptr, cols_s);

  for (int blk = 0; blk < 2; ++blk) {
    spmm_relu<<<20000, 256, 0, stream>>>(row_ptr, cols_s, xb, y);
    gemm_kernel<0><<<625, 256, 0, stream>>>(xb, y, WtCat, biasCat, 2 * blk, rB, nullptr,
                                            nullptr, nullptr, nullptr, nullptr, nullptr, nullptr);
    spmm_plain<<<20000, 256, 0, stream>>>(row_ptr, cols_s, rB, y);
    if (blk == 0)
      gemm_kernel<1><<<625, 256, 0, stream>>>(rB, y, WtCat, biasCat, 1, nullptr, xb,
                                              nullptr, nullptr, nullptr, nullptr, nullptr, nullptr);
    else
      gemm_kernel<2><<<625, 256, 0, stream>>>(rB, y, WtCat, biasCat, 3, nullptr, xb,
                                              zf4, zs4, Wf_o, Ws_o, bf_o, bs_o);
  }
  spmm3_kernel<<<(BN + 255) / 256, 256, 0, stream>>>(row_ptr, cols_s, zf4, zs4, out);
}